// Round 3
// baseline (788.615 us; speedup 1.0000x reference)
//
#include <hip/hip_runtime.h>

#define N_NODES 50000
#define N_EDGES 800000
#define DIM 128
#define NUM_GRAPHS 128

// ================= degree / dinv precompute =================

__global__ __launch_bounds__(256) void k_init(float* deg, int* counts, int n) {
    int i = blockIdx.x * 256 + threadIdx.x;
    if (i < n) { deg[i] = 1.0f; counts[i] = 0; }  // self-loop weight, hist=0
}

// fused: deg += attr  and  counts += 1  per in-edge
__global__ __launch_bounds__(256) void k_deg_hist(const int* __restrict__ dst,
                                                  const float* __restrict__ attr,
                                                  float* deg, int* counts, int E) {
    int e = blockIdx.x * 256 + threadIdx.x;
    if (e < E) {
        int d = dst[e];
        atomicAdd(&deg[d], attr[e]);
        atomicAdd(&counts[d], 1);
    }
}

__global__ __launch_bounds__(256) void k_dinv(float* deg, int n) {
    int i = blockIdx.x * 256 + threadIdx.x;
    if (i < n) {
        float d0 = deg[i];
        deg[i] = d0 > 0.f ? rsqrtf(fmaxf(d0, 1e-12f)) : 0.f;
    }
}

// ================= CSR build (sort edges by dst, on device, every call) ====

__global__ __launch_bounds__(256) void k_zero_int(int* p, int n) {
    int i = blockIdx.x * 256 + threadIdx.x;
    if (i < n) p[i] = 0;
}

// 3-kernel exclusive scan over counts[n] -> offs[n]
__global__ __launch_bounds__(256) void k_scan1(const int* __restrict__ counts,
                                               int* __restrict__ offs,
                                               int* __restrict__ partials, int n) {
    __shared__ int tmp[256];
    int t = threadIdx.x;
    int gid = blockIdx.x * 256 + t;
    int v = gid < n ? counts[gid] : 0;
    tmp[t] = v;
    __syncthreads();
    for (int off = 1; off < 256; off <<= 1) {
        int add = (t >= off) ? tmp[t - off] : 0;
        __syncthreads();
        tmp[t] += add;
        __syncthreads();
    }
    if (gid < n) offs[gid] = tmp[t] - v;  // exclusive within block
    if (t == 255) partials[blockIdx.x] = tmp[255];
}

__global__ __launch_bounds__(256) void k_scan2(int* partials, int nb) {  // nb <= 256
    __shared__ int tmp[256];
    int t = threadIdx.x;
    int v = t < nb ? partials[t] : 0;
    tmp[t] = v;
    __syncthreads();
    for (int off = 1; off < 256; off <<= 1) {
        int add = (t >= off) ? tmp[t - off] : 0;
        __syncthreads();
        tmp[t] += add;
        __syncthreads();
    }
    if (t < nb) partials[t] = tmp[t] - v;  // exclusive
}

__global__ __launch_bounds__(256) void k_scan3(int* __restrict__ offs,
                                               const int* __restrict__ partials, int n) {
    int gid = blockIdx.x * 256 + threadIdx.x;
    if (gid < n) offs[gid] += partials[blockIdx.x];
}

// scatter edges to dst-sorted arrays; computes norm inline
__global__ __launch_bounds__(256) void k_scatter_edges(const int* __restrict__ src,
                                                       const int* __restrict__ dst,
                                                       const float* __restrict__ attr,
                                                       const float* __restrict__ dinv,
                                                       const int* __restrict__ offs,
                                                       int* cur,
                                                       unsigned short* __restrict__ src_s,
                                                       float* __restrict__ nrm_s, int E) {
    int e = blockIdx.x * 256 + threadIdx.x;
    if (e >= E) return;
    int s = src[e];
    int d = dst[e];
    int p = offs[d] + atomicAdd(&cur[d], 1);
    src_s[p] = (unsigned short)s;
    nrm_s[p] = dinv[s] * attr[e] * dinv[d];
}

// ================= GEMM (N x 128) @ (128 x 128), fp32, W in LDS ============

__global__ __launch_bounds__(256) void k_gemm(const float* __restrict__ A,
                                              const float* __restrict__ W,
                                              float* __restrict__ H, int n) {
    __shared__ float4 sW[128 * 32];  // 64 KB
    int tid = threadIdx.x;
    const float4* W4 = (const float4*)W;
#pragma unroll
    for (int i = 0; i < 16; i++) sW[tid + i * 256] = W4[tid + i * 256];
    __syncthreads();

    int tx = tid & 31;   // cols 4*tx .. 4*tx+3
    int ty = tid >> 5;   // 8 row groups of 4 rows
    int row0 = blockIdx.x * 32 + ty * 4;

    const float4* Ar[4];
#pragma unroll
    for (int r = 0; r < 4; r++) {
        int rr = row0 + r;
        if (rr >= n) rr = n - 1;
        Ar[r] = (const float4*)(A + (size_t)rr * DIM);
    }

    float4 acc[4];
#pragma unroll
    for (int r = 0; r < 4; r++) acc[r] = make_float4(0.f, 0.f, 0.f, 0.f);

    for (int k4 = 0; k4 < 32; k4++) {
        float4 w0 = sW[(4 * k4 + 0) * 32 + tx];
        float4 w1 = sW[(4 * k4 + 1) * 32 + tx];
        float4 w2 = sW[(4 * k4 + 2) * 32 + tx];
        float4 w3 = sW[(4 * k4 + 3) * 32 + tx];
#pragma unroll
        for (int r = 0; r < 4; r++) {
            float4 a = Ar[r][k4];
            acc[r].x += a.x * w0.x + a.y * w1.x + a.z * w2.x + a.w * w3.x;
            acc[r].y += a.x * w0.y + a.y * w1.y + a.z * w2.y + a.w * w3.y;
            acc[r].z += a.x * w0.z + a.y * w1.z + a.z * w2.z + a.w * w3.z;
            acc[r].w += a.x * w0.w + a.y * w1.w + a.z * w2.w + a.w * w3.w;
        }
    }

#pragma unroll
    for (int r = 0; r < 4; r++) {
        int rr = row0 + r;
        if (rr < n) ((float4*)(H + (size_t)rr * DIM))[tx] = acc[r];
    }
}

// ===== CSR gather: out[d] = relu(bias + dinv[d]^2 h[d] + sum nrm*h[src]) =====
// 8 lanes per node x 4 column groups (32 cols each). cg = blockIdx & 3 so that
// with round-robin block->XCD mapping each XCD touches only a 6.4 MB column
// slice of H (better per-XCD L2 hit rate). 8 independent edge streams per wave
// x 4-deep unroll = high memory-level parallelism (latency-bound fix).

template <bool POOL>
__global__ __launch_bounds__(256) void k_gather(const float* __restrict__ H,
                                                const int* __restrict__ offs,
                                                const unsigned short* __restrict__ srcs,
                                                const float* __restrict__ nrm,
                                                const float* __restrict__ dinv,
                                                const float* __restrict__ bias,
                                                const int* __restrict__ batch,
                                                float* __restrict__ OUT,
                                                float* gsum, float* cnt, int n) {
    int tid = threadIdx.x;
    int cg = blockIdx.x & 3;                    // column group (XCD-affine)
    int i = (blockIdx.x >> 2) * 32 + (tid >> 3);  // node
    int c = tid & 7;                            // float4 index within group
    if (i >= n) return;
    int col = cg * 8 + c;                       // float4 column in [0,32)
    const float4* H4 = (const float4*)H;

    float di = dinv[i];
    float sw = di * di;
    float4 self = H4[(size_t)i * 32 + col];
    float4 acc = make_float4(sw * self.x, sw * self.y, sw * self.z, sw * self.w);

    int j = offs[i];
    int end = (i == n - 1) ? N_EDGES : offs[i + 1];

    for (; j + 3 < end; j += 4) {
        int s0 = srcs[j + 0];
        int s1 = srcs[j + 1];
        int s2 = srcs[j + 2];
        int s3 = srcs[j + 3];
        float w0 = nrm[j + 0];
        float w1 = nrm[j + 1];
        float w2 = nrm[j + 2];
        float w3 = nrm[j + 3];
        float4 v0 = H4[(size_t)s0 * 32 + col];
        float4 v1 = H4[(size_t)s1 * 32 + col];
        float4 v2 = H4[(size_t)s2 * 32 + col];
        float4 v3 = H4[(size_t)s3 * 32 + col];
        acc.x += w0 * v0.x + w1 * v1.x + w2 * v2.x + w3 * v3.x;
        acc.y += w0 * v0.y + w1 * v1.y + w2 * v2.y + w3 * v3.y;
        acc.z += w0 * v0.z + w1 * v1.z + w2 * v2.z + w3 * v3.z;
        acc.w += w0 * v0.w + w1 * v1.w + w2 * v2.w + w3 * v3.w;
    }
    for (; j < end; ++j) {
        int s0 = srcs[j];
        float w0 = nrm[j];
        float4 v0 = H4[(size_t)s0 * 32 + col];
        acc.x += w0 * v0.x;
        acc.y += w0 * v0.y;
        acc.z += w0 * v0.z;
        acc.w += w0 * v0.w;
    }

    float4 bb = ((const float4*)bias)[col];
    acc.x = fmaxf(acc.x + bb.x, 0.f);
    acc.y = fmaxf(acc.y + bb.y, 0.f);
    acc.z = fmaxf(acc.z + bb.z, 0.f);
    acc.w = fmaxf(acc.w + bb.w, 0.f);

    if (POOL) {
        int g = batch[i];
        float* o = gsum + (size_t)g * DIM + col * 4;
        atomicAdd(o + 0, acc.x);
        atomicAdd(o + 1, acc.y);
        atomicAdd(o + 2, acc.z);
        atomicAdd(o + 3, acc.w);
        if (cg == 0 && c == 0) atomicAdd(&cnt[g], 1.0f);
    } else {
        ((float4*)OUT)[(size_t)i * 32 + col] = acc;
    }
}

// ================= pooling scratch zero + classifier =================

__global__ __launch_bounds__(256) void k_zero(float* p, int n) {
    int i = blockIdx.x * 256 + threadIdx.x;
    if (i < n) p[i] = 0.f;
}

__global__ __launch_bounds__(128) void k_classifier(const float* __restrict__ gsum,
                                                    const float* __restrict__ cnt,
                                                    const float* __restrict__ Wc1,
                                                    const float* __restrict__ bc1,
                                                    const float* __restrict__ Wc2,
                                                    const float* __restrict__ bc2,
                                                    float* __restrict__ out) {
    int g = blockIdx.x;
    int t = threadIdx.x;  // 128
    __shared__ float gv[128];
    __shared__ float hid[128];
    float inv = 1.0f / fmaxf(cnt[g], 1.0f);
    gv[t] = gsum[(size_t)g * DIM + t] * inv;
    __syncthreads();
    float acc = bc1[t];
    for (int k = 0; k < 128; k++) acc += gv[k] * Wc1[k * 128 + t];
    hid[t] = fmaxf(acc, 0.f);
    __syncthreads();
    if (t < 4) {
        float o = bc2[t];
        for (int k = 0; k < 128; k++) o += hid[k] * Wc2[k * 4 + t];
        out[g * 4 + t] = o;
    }
}

// ================= launch =================

extern "C" void kernel_launch(void* const* d_in, const int* in_sizes, int n_in,
                              void* d_out, int out_size, void* d_ws, size_t ws_size,
                              hipStream_t stream) {
    const float* x     = (const float*)d_in[0];
    const int*   ei    = (const int*)d_in[1];  // [2, E]: src then dst
    const float* attr  = (const float*)d_in[2];
    // d_in[3] edge_weight: unused by reference
    const int*   batch = (const int*)d_in[4];
    const float* W0  = (const float*)d_in[5];
    const float* b0  = (const float*)d_in[6];
    const float* W1  = (const float*)d_in[7];
    const float* b1  = (const float*)d_in[8];
    const float* Wc1 = (const float*)d_in[9];
    const float* bc1 = (const float*)d_in[10];
    const float* Wc2 = (const float*)d_in[11];
    const float* bc2 = (const float*)d_in[12];
    float* out = (float*)d_out;

    char* ws = (char*)d_ws;
    float*          bufH     = (float*)(ws + 0);           // 25,600,000
    float*          bufA     = (float*)(ws + 25600000);    // 25,600,000
    float*          nrm_s    = (float*)(ws + 51200000);    //  3,200,000
    unsigned short* src_s    = (unsigned short*)(ws + 54400000);  // 1,600,000
    float*          dinv     = (float*)(ws + 56000000);    //    200,000
    int*            offs     = (int*)(ws + 56200000);      //    200,064
    int*            counts   = (int*)(ws + 56400064);      //    200,000 (also cursor)
    int*            partials = (int*)(ws + 56600064);      //      1,024
    float*          gsum     = (float*)(ws + 56601088);    //     65,536
    float*          cnt      = (float*)(ws + 56666624);    //        512

    const int* src = ei;
    const int* dst = ei + N_EDGES;

    const int NB_N = (N_NODES + 255) / 256;   // 196
    const int NB_E = (N_EDGES + 255) / 256;   // 3125

    // deg/hist fused precompute
    k_init<<<NB_N, 256, 0, stream>>>(dinv, counts, N_NODES);
    k_deg_hist<<<NB_E, 256, 0, stream>>>(dst, attr, dinv, counts, N_EDGES);
    k_dinv<<<NB_N, 256, 0, stream>>>(dinv, N_NODES);

    // CSR: exclusive scan of counts -> offs; scatter (src, norm) sorted by dst
    k_scan1<<<NB_N, 256, 0, stream>>>(counts, offs, partials, N_NODES);
    k_scan2<<<1, 256, 0, stream>>>(partials, NB_N);
    k_scan3<<<NB_N, 256, 0, stream>>>(offs, partials, N_NODES);
    k_zero_int<<<NB_N, 256, 0, stream>>>(counts, N_NODES);  // reuse as cursor
    k_scatter_edges<<<NB_E, 256, 0, stream>>>(src, dst, attr, dinv, offs, counts,
                                              src_s, nrm_s, N_EDGES);

    // zero pool accumulators (ws is poisoned each call)
    k_zero<<<(NUM_GRAPHS * DIM + NUM_GRAPHS + 255) / 256, 256, 0, stream>>>(
        gsum, NUM_GRAPHS * DIM + NUM_GRAPHS);

    const int NB_GA = ((N_NODES + 31) / 32) * 4;  // 1563 node-blocks x 4 col groups

    // layer 1: gemm + gather(bias+relu fused)
    k_gemm<<<(N_NODES + 31) / 32, 256, 0, stream>>>(x, W0, bufH, N_NODES);
    k_gather<false><<<NB_GA, 256, 0, stream>>>(bufH, offs, src_s, nrm_s, dinv, b0,
                                               batch, bufA, gsum, cnt, N_NODES);

    // layer 2: gemm + gather(bias+relu+mean-pool fused)
    k_gemm<<<(N_NODES + 31) / 32, 256, 0, stream>>>(bufA, W1, bufH, N_NODES);
    k_gather<true><<<NB_GA, 256, 0, stream>>>(bufH, offs, src_s, nrm_s, dinv, b1,
                                              batch, nullptr, gsum, cnt, N_NODES);

    // classifier
    k_classifier<<<NUM_GRAPHS, 128, 0, stream>>>(gsum, cnt, Wc1, bc1, Wc2, bc2, out);
}

// Round 4
// 727.720 us; speedup vs baseline: 1.0837x; 1.0837x over previous
//
#include <hip/hip_runtime.h>

#define N_NODES 50000
#define N_EDGES 800000
#define DIM 128
#define NUM_GRAPHS 128

// ================= degree / dinv precompute =================

__global__ __launch_bounds__(256) void k_init(float* deg, int* counts, int n) {
    int i = blockIdx.x * 256 + threadIdx.x;
    if (i < n) { deg[i] = 1.0f; counts[i] = 0; }  // self-loop weight, hist=0
}

// fused: deg += attr  and  counts += 1  per in-edge
__global__ __launch_bounds__(256) void k_deg_hist(const int* __restrict__ dst,
                                                  const float* __restrict__ attr,
                                                  float* deg, int* counts, int E) {
    int e = blockIdx.x * 256 + threadIdx.x;
    if (e < E) {
        int d = dst[e];
        atomicAdd(&deg[d], attr[e]);
        atomicAdd(&counts[d], 1);
    }
}

__global__ __launch_bounds__(256) void k_dinv(float* deg, int n) {
    int i = blockIdx.x * 256 + threadIdx.x;
    if (i < n) {
        float d0 = deg[i];
        deg[i] = d0 > 0.f ? rsqrtf(fmaxf(d0, 1e-12f)) : 0.f;
    }
}

// ================= CSR build (sort edges by dst, on device, every call) ====

__global__ __launch_bounds__(256) void k_zero_int(int* p, int n) {
    int i = blockIdx.x * 256 + threadIdx.x;
    if (i < n) p[i] = 0;
}

// 3-kernel exclusive scan over counts[n] -> offs[n]
__global__ __launch_bounds__(256) void k_scan1(const int* __restrict__ counts,
                                               int* __restrict__ offs,
                                               int* __restrict__ partials, int n) {
    __shared__ int tmp[256];
    int t = threadIdx.x;
    int gid = blockIdx.x * 256 + t;
    int v = gid < n ? counts[gid] : 0;
    tmp[t] = v;
    __syncthreads();
    for (int off = 1; off < 256; off <<= 1) {
        int add = (t >= off) ? tmp[t - off] : 0;
        __syncthreads();
        tmp[t] += add;
        __syncthreads();
    }
    if (gid < n) offs[gid] = tmp[t] - v;  // exclusive within block
    if (t == 255) partials[blockIdx.x] = tmp[255];
}

__global__ __launch_bounds__(256) void k_scan2(int* partials, int nb) {  // nb <= 256
    __shared__ int tmp[256];
    int t = threadIdx.x;
    int v = t < nb ? partials[t] : 0;
    tmp[t] = v;
    __syncthreads();
    for (int off = 1; off < 256; off <<= 1) {
        int add = (t >= off) ? tmp[t - off] : 0;
        __syncthreads();
        tmp[t] += add;
        __syncthreads();
    }
    if (t < nb) partials[t] = tmp[t] - v;  // exclusive
}

__global__ __launch_bounds__(256) void k_scan3(int* __restrict__ offs,
                                               const int* __restrict__ partials, int n) {
    int gid = blockIdx.x * 256 + threadIdx.x;
    if (gid < n) offs[gid] += partials[blockIdx.x];
}

// scatter edges to dst-sorted arrays; computes norm inline
__global__ __launch_bounds__(256) void k_scatter_edges(const int* __restrict__ src,
                                                       const int* __restrict__ dst,
                                                       const float* __restrict__ attr,
                                                       const float* __restrict__ dinv,
                                                       const int* __restrict__ offs,
                                                       int* cur,
                                                       unsigned short* __restrict__ src_s,
                                                       float* __restrict__ nrm_s, int E) {
    int e = blockIdx.x * 256 + threadIdx.x;
    if (e >= E) return;
    int s = src[e];
    int d = dst[e];
    int p = offs[d] + atomicAdd(&cur[d], 1);
    src_s[p] = (unsigned short)s;
    nrm_s[p] = dinv[s] * attr[e] * dinv[d];
}

// ================= GEMM (N x 128) @ (128 x 128), fp32, W in LDS ============

__global__ __launch_bounds__(256) void k_gemm(const float* __restrict__ A,
                                              const float* __restrict__ W,
                                              float* __restrict__ H, int n) {
    __shared__ float4 sW[128 * 32];  // 64 KB
    int tid = threadIdx.x;
    const float4* W4 = (const float4*)W;
#pragma unroll
    for (int i = 0; i < 16; i++) sW[tid + i * 256] = W4[tid + i * 256];
    __syncthreads();

    int tx = tid & 31;   // cols 4*tx .. 4*tx+3
    int ty = tid >> 5;   // 8 row groups of 4 rows
    int row0 = blockIdx.x * 32 + ty * 4;

    const float4* Ar[4];
#pragma unroll
    for (int r = 0; r < 4; r++) {
        int rr = row0 + r;
        if (rr >= n) rr = n - 1;
        Ar[r] = (const float4*)(A + (size_t)rr * DIM);
    }

    float4 acc[4];
#pragma unroll
    for (int r = 0; r < 4; r++) acc[r] = make_float4(0.f, 0.f, 0.f, 0.f);

    for (int k4 = 0; k4 < 32; k4++) {
        float4 w0 = sW[(4 * k4 + 0) * 32 + tx];
        float4 w1 = sW[(4 * k4 + 1) * 32 + tx];
        float4 w2 = sW[(4 * k4 + 2) * 32 + tx];
        float4 w3 = sW[(4 * k4 + 3) * 32 + tx];
#pragma unroll
        for (int r = 0; r < 4; r++) {
            float4 a = Ar[r][k4];
            acc[r].x += a.x * w0.x + a.y * w1.x + a.z * w2.x + a.w * w3.x;
            acc[r].y += a.x * w0.y + a.y * w1.y + a.z * w2.y + a.w * w3.y;
            acc[r].z += a.x * w0.z + a.y * w1.z + a.z * w2.z + a.w * w3.z;
            acc[r].w += a.x * w0.w + a.y * w1.w + a.z * w2.w + a.w * w3.w;
        }
    }

#pragma unroll
    for (int r = 0; r < 4; r++) {
        int rr = row0 + r;
        if (rr < n) ((float4*)(H + (size_t)rr * DIM))[tx] = acc[r];
    }
}

// ===== CSR gather: out[d] = relu(bias + dinv[d]^2 h[d] + sum nrm*h[src]) =====
// 32 lanes per node (one coherent 512 B row per load instruction).
// 8-deep PREDICATED pipeline: batches of 8 edges with index clamped to end-1
// and weight 0 beyond the list (uniform predicate per half-wave, no divergent
// remainder) -> 8 independent row loads in flight per half-wave.

template <bool POOL>
__global__ __launch_bounds__(256) void k_gather(const float* __restrict__ H,
                                                const int* __restrict__ offs,
                                                const unsigned short* __restrict__ srcs,
                                                const float* __restrict__ nrm,
                                                const float* __restrict__ dinv,
                                                const float* __restrict__ bias,
                                                const int* __restrict__ batch,
                                                float* __restrict__ OUT,
                                                float* gsum, float* cnt, int n) {
    int idx = blockIdx.x * 256 + threadIdx.x;
    int i = idx >> 5;
    int lane = idx & 31;
    if (i >= n) return;
    const float4* H4 = (const float4*)H;

    float di = dinv[i];
    float sw = di * di;
    float4 self = H4[(size_t)i * 32 + lane];
    float4 acc = make_float4(sw * self.x, sw * self.y, sw * self.z, sw * self.w);

    int j0 = offs[i];
    int end = (i == n - 1) ? N_EDGES : offs[i + 1];

    for (int j = j0; j < end; j += 8) {
        int s[8];
        float w[8];
#pragma unroll
        for (int k = 0; k < 8; k++) {
            int jj = j + k;
            bool valid = jj < end;
            int jc = valid ? jj : (end - 1);
            s[k] = srcs[jc];
            w[k] = valid ? nrm[jc] : 0.f;
        }
        float4 v[8];
#pragma unroll
        for (int k = 0; k < 8; k++) v[k] = H4[(size_t)s[k] * 32 + lane];
#pragma unroll
        for (int k = 0; k < 8; k++) {
            acc.x += w[k] * v[k].x;
            acc.y += w[k] * v[k].y;
            acc.z += w[k] * v[k].z;
            acc.w += w[k] * v[k].w;
        }
    }

    float4 bb = ((const float4*)bias)[lane];
    acc.x = fmaxf(acc.x + bb.x, 0.f);
    acc.y = fmaxf(acc.y + bb.y, 0.f);
    acc.z = fmaxf(acc.z + bb.z, 0.f);
    acc.w = fmaxf(acc.w + bb.w, 0.f);

    if (POOL) {
        int g = batch[i];
        float* o = gsum + (size_t)g * DIM + lane * 4;
        atomicAdd(o + 0, acc.x);
        atomicAdd(o + 1, acc.y);
        atomicAdd(o + 2, acc.z);
        atomicAdd(o + 3, acc.w);
        if (lane == 0) atomicAdd(&cnt[g], 1.0f);
    } else {
        ((float4*)OUT)[(size_t)i * 32 + lane] = acc;
    }
}

// ================= pooling scratch zero + classifier =================

__global__ __launch_bounds__(256) void k_zero(float* p, int n) {
    int i = blockIdx.x * 256 + threadIdx.x;
    if (i < n) p[i] = 0.f;
}

__global__ __launch_bounds__(128) void k_classifier(const float* __restrict__ gsum,
                                                    const float* __restrict__ cnt,
                                                    const float* __restrict__ Wc1,
                                                    const float* __restrict__ bc1,
                                                    const float* __restrict__ Wc2,
                                                    const float* __restrict__ bc2,
                                                    float* __restrict__ out) {
    int g = blockIdx.x;
    int t = threadIdx.x;  // 128
    __shared__ float gv[128];
    __shared__ float hid[128];
    float inv = 1.0f / fmaxf(cnt[g], 1.0f);
    gv[t] = gsum[(size_t)g * DIM + t] * inv;
    __syncthreads();
    float acc = bc1[t];
    for (int k = 0; k < 128; k++) acc += gv[k] * Wc1[k * 128 + t];
    hid[t] = fmaxf(acc, 0.f);
    __syncthreads();
    if (t < 4) {
        float o = bc2[t];
        for (int k = 0; k < 128; k++) o += hid[k] * Wc2[k * 4 + t];
        out[g * 4 + t] = o;
    }
}

// ================= launch =================

extern "C" void kernel_launch(void* const* d_in, const int* in_sizes, int n_in,
                              void* d_out, int out_size, void* d_ws, size_t ws_size,
                              hipStream_t stream) {
    const float* x     = (const float*)d_in[0];
    const int*   ei    = (const int*)d_in[1];  // [2, E]: src then dst
    const float* attr  = (const float*)d_in[2];
    // d_in[3] edge_weight: unused by reference
    const int*   batch = (const int*)d_in[4];
    const float* W0  = (const float*)d_in[5];
    const float* b0  = (const float*)d_in[6];
    const float* W1  = (const float*)d_in[7];
    const float* b1  = (const float*)d_in[8];
    const float* Wc1 = (const float*)d_in[9];
    const float* bc1 = (const float*)d_in[10];
    const float* Wc2 = (const float*)d_in[11];
    const float* bc2 = (const float*)d_in[12];
    float* out = (float*)d_out;

    char* ws = (char*)d_ws;
    float*          bufH     = (float*)(ws + 0);           // 25,600,000
    float*          bufA     = (float*)(ws + 25600000);    // 25,600,000
    float*          nrm_s    = (float*)(ws + 51200000);    //  3,200,000
    unsigned short* src_s    = (unsigned short*)(ws + 54400000);  // 1,600,000
    float*          dinv     = (float*)(ws + 56000000);    //    200,000
    int*            offs     = (int*)(ws + 56200000);      //    200,064
    int*            counts   = (int*)(ws + 56400064);      //    200,000 (also cursor)
    int*            partials = (int*)(ws + 56600064);      //      1,024
    float*          gsum     = (float*)(ws + 56601088);    //     65,536
    float*          cnt      = (float*)(ws + 56666624);    //        512

    const int* src = ei;
    const int* dst = ei + N_EDGES;

    const int NB_N = (N_NODES + 255) / 256;   // 196
    const int NB_E = (N_EDGES + 255) / 256;   // 3125

    // deg/hist fused precompute
    k_init<<<NB_N, 256, 0, stream>>>(dinv, counts, N_NODES);
    k_deg_hist<<<NB_E, 256, 0, stream>>>(dst, attr, dinv, counts, N_EDGES);
    k_dinv<<<NB_N, 256, 0, stream>>>(dinv, N_NODES);

    // CSR: exclusive scan of counts -> offs; scatter (src, norm) sorted by dst
    k_scan1<<<NB_N, 256, 0, stream>>>(counts, offs, partials, N_NODES);
    k_scan2<<<1, 256, 0, stream>>>(partials, NB_N);
    k_scan3<<<NB_N, 256, 0, stream>>>(offs, partials, N_NODES);
    k_zero_int<<<NB_N, 256, 0, stream>>>(counts, N_NODES);  // reuse as cursor
    k_scatter_edges<<<NB_E, 256, 0, stream>>>(src, dst, attr, dinv, offs, counts,
                                              src_s, nrm_s, N_EDGES);

    // zero pool accumulators (ws is poisoned each call)
    k_zero<<<(NUM_GRAPHS * DIM + NUM_GRAPHS + 255) / 256, 256, 0, stream>>>(
        gsum, NUM_GRAPHS * DIM + NUM_GRAPHS);

    const int NB_G = (N_NODES * 32 + 255) / 256;  // 6250

    // layer 1: gemm + gather(bias+relu fused)
    k_gemm<<<(N_NODES + 31) / 32, 256, 0, stream>>>(x, W0, bufH, N_NODES);
    k_gather<false><<<NB_G, 256, 0, stream>>>(bufH, offs, src_s, nrm_s, dinv, b0,
                                              batch, bufA, gsum, cnt, N_NODES);

    // layer 2: gemm + gather(bias+relu+mean-pool fused)
    k_gemm<<<(N_NODES + 31) / 32, 256, 0, stream>>>(bufA, W1, bufH, N_NODES);
    k_gather<true><<<NB_G, 256, 0, stream>>>(bufH, offs, src_s, nrm_s, dinv, b1,
                                             batch, nullptr, gsum, cnt, N_NODES);

    // classifier
    k_classifier<<<NUM_GRAPHS, 128, 0, stream>>>(gsum, cnt, Wc1, bc1, Wc2, bc2, out);
}

// Round 5
// 670.608 us; speedup vs baseline: 1.1760x; 1.0852x over previous
//
#include <hip/hip_runtime.h>
#include <hip/hip_fp16.h>

#define N_NODES 50000
#define N_EDGES 800000
#define DIM 128
#define NUM_GRAPHS 128

// ================= degree / dinv precompute =================

__global__ __launch_bounds__(256) void k_init(float* deg, int* counts, int n) {
    int i = blockIdx.x * 256 + threadIdx.x;
    if (i < n) { deg[i] = 1.0f; counts[i] = 0; }  // self-loop weight, hist=0
}

// fused: deg += attr  and  counts += 1  per in-edge
__global__ __launch_bounds__(256) void k_deg_hist(const int* __restrict__ dst,
                                                  const float* __restrict__ attr,
                                                  float* deg, int* counts, int E) {
    int e = blockIdx.x * 256 + threadIdx.x;
    if (e < E) {
        int d = dst[e];
        atomicAdd(&deg[d], attr[e]);
        atomicAdd(&counts[d], 1);
    }
}

__global__ __launch_bounds__(256) void k_dinv(float* deg, int n) {
    int i = blockIdx.x * 256 + threadIdx.x;
    if (i < n) {
        float d0 = deg[i];
        deg[i] = d0 > 0.f ? rsqrtf(fmaxf(d0, 1e-12f)) : 0.f;
    }
}

// ================= CSR build (sort edges by dst, on device, every call) ====

__global__ __launch_bounds__(256) void k_zero_int(int* p, int n) {
    int i = blockIdx.x * 256 + threadIdx.x;
    if (i < n) p[i] = 0;
}

// 3-kernel exclusive scan over counts[n] -> offs[n]
__global__ __launch_bounds__(256) void k_scan1(const int* __restrict__ counts,
                                               int* __restrict__ offs,
                                               int* __restrict__ partials, int n) {
    __shared__ int tmp[256];
    int t = threadIdx.x;
    int gid = blockIdx.x * 256 + t;
    int v = gid < n ? counts[gid] : 0;
    tmp[t] = v;
    __syncthreads();
    for (int off = 1; off < 256; off <<= 1) {
        int add = (t >= off) ? tmp[t - off] : 0;
        __syncthreads();
        tmp[t] += add;
        __syncthreads();
    }
    if (gid < n) offs[gid] = tmp[t] - v;  // exclusive within block
    if (t == 255) partials[blockIdx.x] = tmp[255];
}

__global__ __launch_bounds__(256) void k_scan2(int* partials, int nb) {  // nb <= 256
    __shared__ int tmp[256];
    int t = threadIdx.x;
    int v = t < nb ? partials[t] : 0;
    tmp[t] = v;
    __syncthreads();
    for (int off = 1; off < 256; off <<= 1) {
        int add = (t >= off) ? tmp[t - off] : 0;
        __syncthreads();
        tmp[t] += add;
        __syncthreads();
    }
    if (t < nb) partials[t] = tmp[t] - v;  // exclusive
}

__global__ __launch_bounds__(256) void k_scan3(int* __restrict__ offs,
                                               const int* __restrict__ partials, int n) {
    int gid = blockIdx.x * 256 + threadIdx.x;
    if (gid < n) offs[gid] += partials[blockIdx.x];
}

// scatter edges to dst-sorted array; packs (src:u16 | norm:fp16) per edge
__global__ __launch_bounds__(256) void k_scatter_edges(const int* __restrict__ src,
                                                       const int* __restrict__ dst,
                                                       const float* __restrict__ attr,
                                                       const float* __restrict__ dinv,
                                                       const int* __restrict__ offs,
                                                       int* cur,
                                                       unsigned int* __restrict__ epack,
                                                       int E) {
    int e = blockIdx.x * 256 + threadIdx.x;
    if (e >= E) return;
    int s = src[e];
    int d = dst[e];
    int p = offs[d] + atomicAdd(&cur[d], 1);
    __half hn = __float2half_rn(dinv[s] * attr[e] * dinv[d]);
    unsigned short us = *reinterpret_cast<unsigned short*>(&hn);
    epack[p] = ((unsigned int)us << 16) | (unsigned int)s;
}

// ========= GEMM (N x 128) @ (128 x 128), fp32 math, fp16 output table =======

__global__ __launch_bounds__(256) void k_gemm16(const float* __restrict__ A,
                                                const float* __restrict__ W,
                                                __half* __restrict__ H, int n) {
    __shared__ float4 sW[128 * 32];  // 64 KB
    int tid = threadIdx.x;
    const float4* W4 = (const float4*)W;
#pragma unroll
    for (int i = 0; i < 16; i++) sW[tid + i * 256] = W4[tid + i * 256];
    __syncthreads();

    int tx = tid & 31;   // cols 4*tx .. 4*tx+3
    int ty = tid >> 5;   // 8 row groups of 4 rows
    int row0 = blockIdx.x * 32 + ty * 4;

    const float4* Ar[4];
#pragma unroll
    for (int r = 0; r < 4; r++) {
        int rr = row0 + r;
        if (rr >= n) rr = n - 1;
        Ar[r] = (const float4*)(A + (size_t)rr * DIM);
    }

    float4 acc[4];
#pragma unroll
    for (int r = 0; r < 4; r++) acc[r] = make_float4(0.f, 0.f, 0.f, 0.f);

    for (int k4 = 0; k4 < 32; k4++) {
        float4 w0 = sW[(4 * k4 + 0) * 32 + tx];
        float4 w1 = sW[(4 * k4 + 1) * 32 + tx];
        float4 w2 = sW[(4 * k4 + 2) * 32 + tx];
        float4 w3 = sW[(4 * k4 + 3) * 32 + tx];
#pragma unroll
        for (int r = 0; r < 4; r++) {
            float4 a = Ar[r][k4];
            acc[r].x += a.x * w0.x + a.y * w1.x + a.z * w2.x + a.w * w3.x;
            acc[r].y += a.x * w0.y + a.y * w1.y + a.z * w2.y + a.w * w3.y;
            acc[r].z += a.x * w0.z + a.y * w1.z + a.z * w2.z + a.w * w3.z;
            acc[r].w += a.x * w0.w + a.y * w1.w + a.z * w2.w + a.w * w3.w;
        }
    }

#pragma unroll
    for (int r = 0; r < 4; r++) {
        int rr = row0 + r;
        if (rr < n) {
            __half2 h01 = __floats2half2_rn(acc[r].x, acc[r].y);
            __half2 h23 = __floats2half2_rn(acc[r].z, acc[r].w);
            uint2 pk;
            pk.x = *reinterpret_cast<unsigned int*>(&h01);
            pk.y = *reinterpret_cast<unsigned int*>(&h23);
            ((uint2*)(H + (size_t)rr * DIM))[tx] = pk;  // 8B/lane, 256B/row
        }
    }
}

// ===== CSR gather: out[d] = relu(bias + dinv[d]^2 h[d] + sum nrm*h[src]) =====
// fp16 table (256 B rows, 4 cache lines), fp32 accumulation. 32 lanes/node,
// 8-deep predicated pipeline (8 coherent row loads in flight per half-wave).

__device__ __forceinline__ float2 unpack_h2(unsigned int u) {
    __half2 h = *reinterpret_cast<__half2*>(&u);
    return __half22float2(h);
}

template <bool POOL>
__global__ __launch_bounds__(256) void k_gather(const __half* __restrict__ H,
                                                const int* __restrict__ offs,
                                                const unsigned int* __restrict__ epack,
                                                const float* __restrict__ dinv,
                                                const float* __restrict__ bias,
                                                const int* __restrict__ batch,
                                                float* __restrict__ OUT,
                                                float* gsum, float* cnt, int n) {
    int idx = blockIdx.x * 256 + threadIdx.x;
    int i = idx >> 5;
    int lane = idx & 31;
    if (i >= n) return;
    const uint2* H8 = (const uint2*)H;  // one row = 32 uint2 (8B/lane)

    float di = dinv[i];
    float sw = di * di;
    uint2 selfraw = H8[(size_t)i * 32 + lane];
    float2 s01 = unpack_h2(selfraw.x);
    float2 s23 = unpack_h2(selfraw.y);
    float4 acc = make_float4(sw * s01.x, sw * s01.y, sw * s23.x, sw * s23.y);

    int j0 = offs[i];
    int end = (i == n - 1) ? N_EDGES : offs[i + 1];

    for (int j = j0; j < end; j += 8) {
        int s[8];
        float w[8];
#pragma unroll
        for (int k = 0; k < 8; k++) {
            int jj = j + k;
            bool valid = jj < end;
            int jc = valid ? jj : (end - 1);
            unsigned int pe = epack[jc];
            s[k] = (int)(pe & 0xffffu);
            __half_raw hr;
            hr.x = (unsigned short)(pe >> 16);
            float wv = __half2float(__half(hr));
            w[k] = valid ? wv : 0.f;
        }
        uint2 v[8];
#pragma unroll
        for (int k = 0; k < 8; k++) v[k] = H8[(size_t)s[k] * 32 + lane];
#pragma unroll
        for (int k = 0; k < 8; k++) {
            float2 f01 = unpack_h2(v[k].x);
            float2 f23 = unpack_h2(v[k].y);
            acc.x += w[k] * f01.x;
            acc.y += w[k] * f01.y;
            acc.z += w[k] * f23.x;
            acc.w += w[k] * f23.y;
        }
    }

    float4 bb = ((const float4*)bias)[lane];
    acc.x = fmaxf(acc.x + bb.x, 0.f);
    acc.y = fmaxf(acc.y + bb.y, 0.f);
    acc.z = fmaxf(acc.z + bb.z, 0.f);
    acc.w = fmaxf(acc.w + bb.w, 0.f);

    if (POOL) {
        int g = batch[i];
        float* o = gsum + (size_t)g * DIM + lane * 4;
        atomicAdd(o + 0, acc.x);
        atomicAdd(o + 1, acc.y);
        atomicAdd(o + 2, acc.z);
        atomicAdd(o + 3, acc.w);
        if (lane == 0) atomicAdd(&cnt[g], 1.0f);
    } else {
        ((float4*)OUT)[(size_t)i * 32 + lane] = acc;
    }
}

// ================= pooling scratch zero + classifier =================

__global__ __launch_bounds__(256) void k_zero(float* p, int n) {
    int i = blockIdx.x * 256 + threadIdx.x;
    if (i < n) p[i] = 0.f;
}

__global__ __launch_bounds__(128) void k_classifier(const float* __restrict__ gsum,
                                                    const float* __restrict__ cnt,
                                                    const float* __restrict__ Wc1,
                                                    const float* __restrict__ bc1,
                                                    const float* __restrict__ Wc2,
                                                    const float* __restrict__ bc2,
                                                    float* __restrict__ out) {
    int g = blockIdx.x;
    int t = threadIdx.x;  // 128
    __shared__ float gv[128];
    __shared__ float hid[128];
    float inv = 1.0f / fmaxf(cnt[g], 1.0f);
    gv[t] = gsum[(size_t)g * DIM + t] * inv;
    __syncthreads();
    float acc = bc1[t];
    for (int k = 0; k < 128; k++) acc += gv[k] * Wc1[k * 128 + t];
    hid[t] = fmaxf(acc, 0.f);
    __syncthreads();
    if (t < 4) {
        float o = bc2[t];
        for (int k = 0; k < 128; k++) o += hid[k] * Wc2[k * 4 + t];
        out[g * 4 + t] = o;
    }
}

// ================= launch =================

extern "C" void kernel_launch(void* const* d_in, const int* in_sizes, int n_in,
                              void* d_out, int out_size, void* d_ws, size_t ws_size,
                              hipStream_t stream) {
    const float* x     = (const float*)d_in[0];
    const int*   ei    = (const int*)d_in[1];  // [2, E]: src then dst
    const float* attr  = (const float*)d_in[2];
    // d_in[3] edge_weight: unused by reference
    const int*   batch = (const int*)d_in[4];
    const float* W0  = (const float*)d_in[5];
    const float* b0  = (const float*)d_in[6];
    const float* W1  = (const float*)d_in[7];
    const float* b1  = (const float*)d_in[8];
    const float* Wc1 = (const float*)d_in[9];
    const float* bc1 = (const float*)d_in[10];
    const float* Wc2 = (const float*)d_in[11];
    const float* bc2 = (const float*)d_in[12];
    float* out = (float*)d_out;

    char* ws = (char*)d_ws;
    __half*       bufH16   = (__half*)(ws + 0);            // 12,800,000
    float*        bufA     = (float*)(ws + 12800000);      // 25,600,000
    unsigned int* epack    = (unsigned int*)(ws + 38400000);  // 3,200,000
    float*        dinv     = (float*)(ws + 41600000);      //    200,000
    int*          offs     = (int*)(ws + 41800000);        //    200,064
    int*          counts   = (int*)(ws + 42000064);        //    200,000 (also cursor)
    int*          partials = (int*)(ws + 42200064);        //      1,024
    float*        gsum     = (float*)(ws + 42201088);      //     65,536
    float*        cnt      = (float*)(ws + 42266624);      //        512

    const int* src = ei;
    const int* dst = ei + N_EDGES;

    const int NB_N = (N_NODES + 255) / 256;   // 196
    const int NB_E = (N_EDGES + 255) / 256;   // 3125

    // deg/hist fused precompute
    k_init<<<NB_N, 256, 0, stream>>>(dinv, counts, N_NODES);
    k_deg_hist<<<NB_E, 256, 0, stream>>>(dst, attr, dinv, counts, N_EDGES);
    k_dinv<<<NB_N, 256, 0, stream>>>(dinv, N_NODES);

    // CSR: exclusive scan of counts -> offs; scatter packed (src|norm) by dst
    k_scan1<<<NB_N, 256, 0, stream>>>(counts, offs, partials, N_NODES);
    k_scan2<<<1, 256, 0, stream>>>(partials, NB_N);
    k_scan3<<<NB_N, 256, 0, stream>>>(offs, partials, N_NODES);
    k_zero_int<<<NB_N, 256, 0, stream>>>(counts, N_NODES);  // reuse as cursor
    k_scatter_edges<<<NB_E, 256, 0, stream>>>(src, dst, attr, dinv, offs, counts,
                                              epack, N_EDGES);

    // zero pool accumulators (ws is poisoned each call)
    k_zero<<<(NUM_GRAPHS * DIM + NUM_GRAPHS + 255) / 256, 256, 0, stream>>>(
        gsum, NUM_GRAPHS * DIM + NUM_GRAPHS);

    const int NB_G = (N_NODES * 32 + 255) / 256;  // 6250

    // layer 1: gemm(fp16 table) + gather(bias+relu fused)
    k_gemm16<<<(N_NODES + 31) / 32, 256, 0, stream>>>(x, W0, bufH16, N_NODES);
    k_gather<false><<<NB_G, 256, 0, stream>>>(bufH16, offs, epack, dinv, b0,
                                              batch, bufA, gsum, cnt, N_NODES);

    // layer 2: gemm(fp16 table) + gather(bias+relu+mean-pool fused)
    k_gemm16<<<(N_NODES + 31) / 32, 256, 0, stream>>>(bufA, W1, bufH16, N_NODES);
    k_gather<true><<<NB_G, 256, 0, stream>>>(bufH16, offs, epack, dinv, b1,
                                             batch, nullptr, gsum, cnt, N_NODES);

    // classifier
    k_classifier<<<NUM_GRAPHS, 128, 0, stream>>>(gsum, cnt, Wc1, bc1, Wc2, bc2, out);
}